// Round 6
// baseline (430.231 us; speedup 1.0000x reference)
//
#include <hip/hip_runtime.h>
#include <math.h>

typedef __attribute__((ext_vector_type(8))) short bf16x8;
typedef __attribute__((ext_vector_type(4))) float f32x4;
typedef unsigned short u16;
typedef unsigned int u32;

static __device__ __forceinline__ u16 f2bf(float f) {
    unsigned u = __float_as_uint(f);
    unsigned r = (u + 0x7fff + ((u >> 16) & 1)) >> 16;  // RNE
    return (u16)r;
}
static __device__ __forceinline__ float bf2f(u16 h) {
    return __uint_as_float(((unsigned)h) << 16);
}
static __device__ __forceinline__ float pk_lo(u32 u) { return __uint_as_float(u << 16); }
static __device__ __forceinline__ float pk_hi(u32 u) { return __uint_as_float(u & 0xffff0000u); }

// ---------------- CSR build ----------------
__global__ void zero_int_k(int* __restrict__ p, int n) {
    int i = blockIdx.x * 256 + threadIdx.x;
    if (i < n) p[i] = 0;
}
__global__ void count_rank_k(const int* __restrict__ dst, int* __restrict__ counts,
                             u16* __restrict__ rank, int e) {
    int i = blockIdx.x * 256 + threadIdx.x;
    if (i < e) rank[i] = (u16)atomicAdd(&counts[dst[i]], 1);
}
__global__ __launch_bounds__(1024) void scan1_k(const int* __restrict__ counts,
                                                int* __restrict__ offs,
                                                int* __restrict__ bsum,
                                                float* __restrict__ dinv, int n) {
    __shared__ int ws[16];
    int tid = threadIdx.x;
    int i = blockIdx.x * 1024 + tid;
    int lane = tid & 63, w = tid >> 6;
    int c = (i < n) ? counts[i] : 0;
    if (i < n) dinv[i] = rsqrtf((float)c + 1.0f);
    int s = c;
#pragma unroll
    for (int o = 1; o < 64; o <<= 1) { int t = __shfl_up(s, o); if (lane >= o) s += t; }
    if (lane == 63) ws[w] = s;
    __syncthreads();
    if (w == 0) {
        int x = (lane < 16) ? ws[lane] : 0;
#pragma unroll
        for (int o = 1; o < 16; o <<= 1) { int t = __shfl_up(x, o); if (lane >= o) x += t; }
        if (lane < 16) ws[lane] = x;
    }
    __syncthreads();
    int base = (w > 0) ? ws[w - 1] : 0;
    int incl = base + s;
    if (i < n) offs[i + 1] = incl;
    if (tid == 1023) bsum[blockIdx.x] = incl;
}
__global__ void scan2_k(int* __restrict__ bsum, int nb) {
    int lane = threadIdx.x;
    int v = (lane < nb) ? bsum[lane] : 0;
#pragma unroll
    for (int o = 1; o < 64; o <<= 1) { int t = __shfl_up(v, o); if (lane >= o) v += t; }
    if (lane < nb) bsum[lane] = v;
}
__global__ void scan3_k(int* __restrict__ offs, const int* __restrict__ bsum, int n) {
    int i = blockIdx.x * 256 + threadIdx.x;
    if (i == 0) offs[0] = 0;
    if (i < n) {
        int b = i >> 10;
        offs[i + 1] += (b > 0) ? bsum[b - 1] : 0;
    }
}
__global__ void fill2_k(const int* __restrict__ src, const int* __restrict__ dst,
                        const u16* __restrict__ rank, const int* __restrict__ offs,
                        u16* __restrict__ csr, int e) {
    int i = blockIdx.x * 256 + threadIdx.x;
    if (i < e) csr[offs[dst[i]] + (int)rank[i]] = (u16)src[i];
}

// ---------------- W prepack (fragment-ordered bf16 hi/lo) ----------------
__global__ void pack_all_k(const float* __restrict__ W0, const float* __restrict__ W1,
                           const float* __restrict__ W2,
                           u16* __restrict__ w0hi, u16* __restrict__ w0lo,
                           u16* __restrict__ w1hi, u16* __restrict__ w1lo,
                           u16* __restrict__ w2hi, u16* __restrict__ w2lo) {
    int i = blockIdx.x * 256 + threadIdx.x;
    const float* W; u16 *hi, *lo; int COLS, cin, idx;
    if (i < 16384)      { W = W0; hi = w0hi; lo = w0lo; COLS = 128; cin = 128; idx = i; }
    else if (i < 32768) { W = W1; hi = w1hi; lo = w1lo; COLS = 128; cin = 128; idx = i - 16384; }
    else if (i < 40960) { W = W2; hi = w2hi; lo = w2lo; COLS = 64;  cin = 40;  idx = i - 32768; }
    else return;
    int k = idx / COLS, col = idx % COLS;
    float v = (col < cin) ? W[k * cin + col] : 0.f;
    u16 h = f2bf(v);
    u16 l = f2bf(v - bf2f(h));
    int ct = col >> 4, ks = k >> 5, ln = (col & 15) + (((k >> 3) & 3) << 4), j = k & 7;
    int pos = (((ct * 4 + ks) * 64 + ln) << 3) + j;
    hi[pos] = h; lo[pos] = l;
}

// slice-major C store: COLS=128 -> [8][N][16] bf16 ; COLS=64 -> [8][N][8] bf16
template<int COLS>
static __device__ __forceinline__ void store_slice(u16* C, int N, int row, int c, float v) {
    constexpr int SH = (COLS == 128) ? 4 : 3;
    constexpr int SC = 1 << SH;
    C[((size_t)(c >> SH) * N + row) * SC + (c & (SC - 1))] = f2bf(v);
}

// ---------------- layer-1 GEMM: fp32 A, hi/lo split (3 MFMA), slice-major bf16 C ----------------
template<int COLS>
__global__ __launch_bounds__(256) void mfma_gemm_f32a_k(const float* __restrict__ A,
                                                        const u16* __restrict__ Whi,
                                                        const u16* __restrict__ Wlo,
                                                        const float* __restrict__ dinv,
                                                        u16* __restrict__ C, int nrows) {
    int wave = threadIdx.x >> 6, lane = threadIdx.x & 63;
    int r0 = blockIdx.x * 64 + wave * 16;
    int arow = min(r0 + (lane & 15), nrows - 1);
    int kbase = (lane >> 4) * 8;

    bf16x8 ahi[4], alo[4];
#pragma unroll
    for (int ks = 0; ks < 4; ++ks) {
        const float* ap = &A[(long)arow * 128 + ks * 32 + kbase];
        float4 f0 = *(const float4*)ap;
        float4 f1 = *(const float4*)(ap + 4);
        float fv[8] = {f0.x, f0.y, f0.z, f0.w, f1.x, f1.y, f1.z, f1.w};
#pragma unroll
        for (int j = 0; j < 8; ++j) {
            u16 h = f2bf(fv[j]);
            ahi[ks][j] = (short)h;
            alo[ks][j] = (short)f2bf(fv[j] - bf2f(h));
        }
    }
    float dscale[4];
#pragma unroll
    for (int r = 0; r < 4; ++r) {
        int orow = r0 + (lane >> 4) * 4 + r;
        dscale[r] = (orow < nrows) ? dinv[orow] : 0.f;
    }
#pragma unroll
    for (int ct = 0; ct < COLS / 16; ct += 2) {
        f32x4 acc0 = {0.f, 0.f, 0.f, 0.f}, acc1 = {0.f, 0.f, 0.f, 0.f};
#pragma unroll
        for (int ks = 0; ks < 4; ++ks) {
            int fo0 = ((ct * 4 + ks) * 64 + lane) * 8;
            int fo1 = (((ct + 1) * 4 + ks) * 64 + lane) * 8;
            bf16x8 bhi0 = *(const bf16x8*)&Whi[fo0];
            bf16x8 blo0 = *(const bf16x8*)&Wlo[fo0];
            bf16x8 bhi1 = *(const bf16x8*)&Whi[fo1];
            bf16x8 blo1 = *(const bf16x8*)&Wlo[fo1];
            acc0 = __builtin_amdgcn_mfma_f32_16x16x32_bf16(ahi[ks], bhi0, acc0, 0, 0, 0);
            acc1 = __builtin_amdgcn_mfma_f32_16x16x32_bf16(ahi[ks], bhi1, acc1, 0, 0, 0);
            acc0 = __builtin_amdgcn_mfma_f32_16x16x32_bf16(alo[ks], bhi0, acc0, 0, 0, 0);
            acc1 = __builtin_amdgcn_mfma_f32_16x16x32_bf16(alo[ks], bhi1, acc1, 0, 0, 0);
            acc0 = __builtin_amdgcn_mfma_f32_16x16x32_bf16(ahi[ks], blo0, acc0, 0, 0, 0);
            acc1 = __builtin_amdgcn_mfma_f32_16x16x32_bf16(ahi[ks], blo1, acc1, 0, 0, 0);
        }
#pragma unroll
        for (int r = 0; r < 4; ++r) {
            int orow = r0 + (lane >> 4) * 4 + r;
            if (orow < nrows) {
                store_slice<COLS>(C, nrows, orow, ct * 16 + (lane & 15), acc0[r] * dscale[r]);
                store_slice<COLS>(C, nrows, orow, (ct + 1) * 16 + (lane & 15), acc1[r] * dscale[r]);
            }
        }
    }
}

// ---------------- layers 2/3 GEMM with fused input bias+LN+ReLU ----------------
// A = agg words [N][64] u32 (word W holds feats 2W,2W+1, pre-LN sums); 2 MFMA; slice-major C
template<int COLS>
__global__ __launch_bounds__(256) void gemm_ln_k(const u32* __restrict__ agg,
                                                 const u16* __restrict__ Whi,
                                                 const u16* __restrict__ Wlo,
                                                 const float* __restrict__ dinv,
                                                 const float* __restrict__ bias,
                                                 const float* __restrict__ g,
                                                 const float* __restrict__ b,
                                                 u16* __restrict__ C, int nrows) {
    int wave = threadIdx.x >> 6, lane = threadIdx.x & 63;
    int r0 = blockIdx.x * 64 + wave * 16;
    int arow = min(r0 + (lane & 15), nrows - 1);
    int kb = lane >> 4;  // 0..3

    const u32* ap = agg + (size_t)arow * 64 + kb * 4;
    float dA = dinv[arow];
    float tv[4][8];
    float ssum = 0.f;
#pragma unroll
    for (int ks = 0; ks < 4; ++ks) {
#pragma unroll
        for (int w2 = 0; w2 < 4; ++w2) {
            u32 u = ap[ks * 16 + w2];
            int wi = ks * 16 + kb * 4 + w2;
            float2 bi = ((const float2*)bias)[wi];
            float t0 = pk_lo(u) * dA + bi.x;
            float t1 = pk_hi(u) * dA + bi.y;
            tv[ks][w2 * 2] = t0; tv[ks][w2 * 2 + 1] = t1;
            ssum += t0 + t1;
        }
    }
    ssum += __shfl_xor(ssum, 16);
    ssum += __shfl_xor(ssum, 32);
    float mu = ssum * (1.f / 128.f);
    float ssq = 0.f;
#pragma unroll
    for (int ks = 0; ks < 4; ++ks)
#pragma unroll
        for (int j = 0; j < 8; ++j) { float d = tv[ks][j] - mu; ssq += d * d; }
    ssq += __shfl_xor(ssq, 16);
    ssq += __shfl_xor(ssq, 32);
    float rstd = rsqrtf(ssq * (1.f / 128.f) + 1e-5f);

    bf16x8 afr[4];
#pragma unroll
    for (int ks = 0; ks < 4; ++ks) {
#pragma unroll
        for (int w2 = 0; w2 < 4; ++w2) {
            int wi = ks * 16 + kb * 4 + w2;
            float2 gv = ((const float2*)g)[wi];
            float2 bv = ((const float2*)b)[wi];
            float y0 = fmaxf(0.f, (tv[ks][w2 * 2] - mu) * rstd * gv.x + bv.x);
            float y1 = fmaxf(0.f, (tv[ks][w2 * 2 + 1] - mu) * rstd * gv.y + bv.y);
            afr[ks][w2 * 2] = (short)f2bf(y0);
            afr[ks][w2 * 2 + 1] = (short)f2bf(y1);
        }
    }

    float dscale[4];
#pragma unroll
    for (int r = 0; r < 4; ++r) {
        int orow = r0 + (lane >> 4) * 4 + r;
        dscale[r] = (orow < nrows) ? dinv[orow] : 0.f;
    }
#pragma unroll
    for (int ct = 0; ct < COLS / 16; ct += 2) {
        f32x4 acc0 = {0.f, 0.f, 0.f, 0.f}, acc1 = {0.f, 0.f, 0.f, 0.f};
#pragma unroll
        for (int ks = 0; ks < 4; ++ks) {
            int fo0 = ((ct * 4 + ks) * 64 + lane) * 8;
            int fo1 = (((ct + 1) * 4 + ks) * 64 + lane) * 8;
            bf16x8 bhi0 = *(const bf16x8*)&Whi[fo0];
            bf16x8 blo0 = *(const bf16x8*)&Wlo[fo0];
            bf16x8 bhi1 = *(const bf16x8*)&Whi[fo1];
            bf16x8 blo1 = *(const bf16x8*)&Wlo[fo1];
            acc0 = __builtin_amdgcn_mfma_f32_16x16x32_bf16(afr[ks], bhi0, acc0, 0, 0, 0);
            acc1 = __builtin_amdgcn_mfma_f32_16x16x32_bf16(afr[ks], bhi1, acc1, 0, 0, 0);
            acc0 = __builtin_amdgcn_mfma_f32_16x16x32_bf16(afr[ks], blo0, acc0, 0, 0, 0);
            acc1 = __builtin_amdgcn_mfma_f32_16x16x32_bf16(afr[ks], blo1, acc1, 0, 0, 0);
        }
#pragma unroll
        for (int r = 0; r < 4; ++r) {
            int orow = r0 + (lane >> 4) * 4 + r;
            if (orow < nrows) {
                store_slice<COLS>(C, nrows, orow, ct * 16 + (lane & 15), acc0[r] * dscale[r]);
                store_slice<COLS>(C, nrows, orow, (ct + 1) * 16 + (lane & 15), acc1[r] * dscale[r]);
            }
        }
    }
}

// ---------------- XCD-affine sliced aggregation ----------------
// slice = blockIdx & 7 (round-robin -> one XCD per slice); one wave per (node, slice).
// WS = u32 words per slice (8 for 16-col slices, 4 for 8-col). Writes pre-LN sums (bf16 pair/word).
template<int WS>
__global__ __launch_bounds__(256) void agg_slice_k(const u32* __restrict__ Csl,
                                                   const int* __restrict__ offs,
                                                   const u16* __restrict__ csr,
                                                   u32* __restrict__ aggout, int n) {
    int s = blockIdx.x & 7;
    int node = (blockIdx.x >> 3) * 4 + (threadIdx.x >> 6);
    if (node >= n) return;
    int l = threadIdx.x & 63;
    int w = l & (WS - 1);
    int t = l / WS;
    constexpr int SLOTS = 64 / WS;
    const u32* C = Csl + (size_t)s * n * WS;
    float ax = 0.f, ay = 0.f;
    if (l < WS) {  // self term
        u32 u = C[(size_t)node * WS + w];
        ax = pk_lo(u); ay = pk_hi(u);
    }
    int beg = offs[node], end = offs[node + 1];
    for (int j = beg; j < end; j += 64) {
        int cnt = min(64, end - j);
        int idx = (l < cnt) ? (int)csr[j + l] : 0;
        for (int k = 0; k < cnt; k += SLOTS) {
            int e = k + t;
            int src = __shfl(idx, e);
            if (e < cnt) {
                u32 u = C[(size_t)src * WS + w];
                ax += pk_lo(u); ay += pk_hi(u);
            }
        }
    }
#pragma unroll
    for (int m = WS; m < 64; m <<= 1) {
        ax += __shfl_xor(ax, m);
        ay += __shfl_xor(ay, m);
    }
    if (l < WS)
        aggout[(size_t)node * (8 * WS) + s * WS + w] = ((u32)f2bf(ay) << 16) | (u32)f2bf(ax);
}

// ---------------- final: bias + log_softmax from agg3 words [N][32] (feats 0..39 valid) ----------------
__global__ __launch_bounds__(256) void lsm2_k(const u32* __restrict__ agg3,
                                              const float* __restrict__ dinv,
                                              const float* __restrict__ b2,
                                              float* __restrict__ out, int n) {
    int wid = (blockIdx.x * 256 + threadIdx.x) >> 6;
    int lane = threadIdx.x & 63;
    if (wid >= n) return;
    float v0 = -INFINITY, v1 = -INFINITY;
    if (lane < 20) {
        u32 u = agg3[(size_t)wid * 32 + lane];
        float dA = dinv[wid];
        float2 bb = ((const float2*)b2)[lane];
        v0 = pk_lo(u) * dA + bb.x;
        v1 = pk_hi(u) * dA + bb.y;
    }
    float m = fmaxf(v0, v1);
#pragma unroll
    for (int off = 32; off; off >>= 1) m = fmaxf(m, __shfl_xor(m, off));
    float e = (lane < 20) ? (expf(v0 - m) + expf(v1 - m)) : 0.f;
#pragma unroll
    for (int off = 32; off; off >>= 1) e += __shfl_xor(e, off);
    float ls = logf(e);
    if (lane < 20)
        ((float2*)out)[(size_t)wid * 20 + lane] = make_float2(v0 - m - ls, v1 - m - ls);
}

extern "C" void kernel_launch(void* const* d_in, const int* in_sizes, int n_in,
                              void* d_out, int out_size, void* d_ws, size_t ws_size,
                              hipStream_t stream) {
    const float* x    = (const float*)d_in[0];
    const float* W0   = (const float*)d_in[1];
    const float* b0   = (const float*)d_in[2];
    const float* W1   = (const float*)d_in[3];
    const float* b1   = (const float*)d_in[4];
    const float* W2   = (const float*)d_in[5];
    const float* b2   = (const float*)d_in[6];
    const float* ln1g = (const float*)d_in[7];
    const float* ln1b = (const float*)d_in[8];
    const float* ln2g = (const float*)d_in[9];
    const float* ln2b = (const float*)d_in[10];
    const int*   ei   = (const int*)d_in[11];

    const int N = in_sizes[0] / 128;   // 50000
    const int E = in_sizes[11] / 2;    // 800000
    const int* esrc = ei;
    const int* edst = ei + E;
    float* out = (float*)d_out;

    const int Npad = ((N + 255) / 256) * 256;

    int* counts  = (int*)d_ws;                        // Npad
    int* offs    = counts + Npad;                     // Npad (N+1 used)
    int* bsum    = offs + Npad;                       // 64
    u16* rank16  = (u16*)(bsum + 64);                 // E
    u16* csr16   = rank16 + E;                        // E
    float* dinv  = (float*)(csr16 + E);               // Npad
    u16* bufC    = (u16*)(dinv + Npad);               // N*128 bf16 (slice-major Cs)
    u32* bufAgg  = (u32*)(bufC + (size_t)N * 128);    // N*64 u32 (pre-LN agg)
    u16* w0hi    = (u16*)(bufAgg + (size_t)N * 64);
    u16* w0lo    = w0hi + 16384;
    u16* w1hi    = w0lo + 16384;
    u16* w1lo    = w1hi + 16384;
    u16* w2hi    = w1lo + 16384;
    u16* w2lo    = w2hi + 8192;

    dim3 blk(256);
    int gN = (N + 255) / 256, gE = (E + 255) / 256;
    int nb1024 = (N + 1023) / 1024;
    int gG = (N + 63) / 64;
    int gA = ((N + 3) / 4) * 8;   // (node-chunk, slice) blocks; slice = blockIdx & 7
    int gW = (N + 3) / 4;

    // ---- CSR build + norm ----
    zero_int_k<<<gN, blk, 0, stream>>>(counts, N);
    count_rank_k<<<gE, blk, 0, stream>>>(edst, counts, rank16, E);
    scan1_k<<<nb1024, 1024, 0, stream>>>(counts, offs, bsum, dinv, N);
    scan2_k<<<1, 64, 0, stream>>>(bsum, nb1024);
    scan3_k<<<gN, blk, 0, stream>>>(offs, bsum, N);
    fill2_k<<<gE, blk, 0, stream>>>(esrc, edst, rank16, offs, csr16, E);

    // ---- W prepack ----
    pack_all_k<<<160, blk, 0, stream>>>(W0, W1, W2, w0hi, w0lo, w1hi, w1lo, w2hi, w2lo);

    // ---- layer 1 ----
    mfma_gemm_f32a_k<128><<<gG, blk, 0, stream>>>(x, w0hi, w0lo, dinv, bufC, N);
    agg_slice_k<8><<<gA, blk, 0, stream>>>((const u32*)bufC, offs, csr16, bufAgg, N);
    // ---- layer 2 (LN1+ReLU fused into A-load) ----
    gemm_ln_k<128><<<gG, blk, 0, stream>>>(bufAgg, w1hi, w1lo, dinv, b0, ln1g, ln1b, bufC, N);
    agg_slice_k<8><<<gA, blk, 0, stream>>>((const u32*)bufC, offs, csr16, bufAgg, N);
    // ---- layer 3 (LN2+ReLU fused into A-load) ----
    gemm_ln_k<64><<<gG, blk, 0, stream>>>(bufAgg, w2hi, w2lo, dinv, b1, ln2g, ln2b, bufC, N);
    agg_slice_k<4><<<gA, blk, 0, stream>>>((const u32*)bufC, offs, csr16, bufAgg, N);
    // ---- output ----
    lsm2_k<<<gW, blk, 0, stream>>>(bufAgg, dinv, b2, out, N);
}

// Round 7
// 207.121 us; speedup vs baseline: 2.0772x; 2.0772x over previous
//
#include <hip/hip_runtime.h>
#include <math.h>

typedef __attribute__((ext_vector_type(8))) short bf16x8;
typedef __attribute__((ext_vector_type(4))) float f32x4;
typedef unsigned short u16;
typedef unsigned int u32;

static __device__ __forceinline__ u16 f2bf(float f) {
    unsigned u = __float_as_uint(f);
    unsigned r = (u + 0x7fff + ((u >> 16) & 1)) >> 16;  // RNE
    return (u16)r;
}
static __device__ __forceinline__ float bf2f(u16 h) {
    return __uint_as_float(((unsigned)h) << 16);
}
static __device__ __forceinline__ float pk_lo(u32 u) { return __uint_as_float(u << 16); }
static __device__ __forceinline__ float pk_hi(u32 u) { return __uint_as_float(u & 0xffff0000u); }

// ---------------- init: zero counts + pack weights (one dispatch) ----------------
// blocks [0,gN): zero; blocks [gN, gN+160): weight prepack (fragment-ordered bf16 hi/lo)
__global__ void init_k(int* __restrict__ counts, int n, int gN,
                       const float* __restrict__ W0, const float* __restrict__ W1,
                       const float* __restrict__ W2,
                       u16* __restrict__ w0hi, u16* __restrict__ w0lo,
                       u16* __restrict__ w1hi, u16* __restrict__ w1lo,
                       u16* __restrict__ w2hi, u16* __restrict__ w2lo) {
    int b = blockIdx.x;
    if (b < gN) {
        int i = b * 256 + threadIdx.x;
        if (i < n) counts[i] = 0;
        return;
    }
    int i = (b - gN) * 256 + threadIdx.x;
    const float* W; u16 *hi, *lo; int COLS, cin, idx;
    if (i < 16384)      { W = W0; hi = w0hi; lo = w0lo; COLS = 128; cin = 128; idx = i; }
    else if (i < 32768) { W = W1; hi = w1hi; lo = w1lo; COLS = 128; cin = 128; idx = i - 16384; }
    else if (i < 40960) { W = W2; hi = w2hi; lo = w2lo; COLS = 64;  cin = 40;  idx = i - 32768; }
    else return;
    int k = idx / COLS, col = idx % COLS;
    float v = (col < cin) ? W[k * cin + col] : 0.f;
    u16 h = f2bf(v);
    u16 l = f2bf(v - bf2f(h));
    int ct = col >> 4, ks = k >> 5, ln = (col & 15) + (((k >> 3) & 3) << 4), j = k & 7;
    int pos = (((ct * 4 + ks) * 64 + ln) << 3) + j;
    hi[pos] = h; lo[pos] = l;
}

// ---------------- CSR build ----------------
__global__ void count_rank_k(const int* __restrict__ dst, int* __restrict__ counts,
                             u16* __restrict__ rank, int e) {
    int i = blockIdx.x * 256 + threadIdx.x;
    if (i < e) rank[i] = (u16)atomicAdd(&counts[dst[i]], 1);
}
// block-local inclusive scan -> offs[i+1]; block totals -> bsum; fused dinv
__global__ __launch_bounds__(1024) void scan1_k(const int* __restrict__ counts,
                                                int* __restrict__ offs,
                                                int* __restrict__ bsum,
                                                float* __restrict__ dinv, int n) {
    __shared__ int ws[16];
    int tid = threadIdx.x;
    int i = blockIdx.x * 1024 + tid;
    int lane = tid & 63, w = tid >> 6;
    int c = (i < n) ? counts[i] : 0;
    if (i < n) dinv[i] = rsqrtf((float)c + 1.0f);
    int s = c;
#pragma unroll
    for (int o = 1; o < 64; o <<= 1) { int t = __shfl_up(s, o); if (lane >= o) s += t; }
    if (lane == 63) ws[w] = s;
    __syncthreads();
    if (w == 0) {
        int x = (lane < 16) ? ws[lane] : 0;
#pragma unroll
        for (int o = 1; o < 16; o <<= 1) { int t = __shfl_up(x, o); if (lane >= o) x += t; }
        if (lane < 16) ws[lane] = x;
    }
    __syncthreads();
    int base = (w > 0) ? ws[w - 1] : 0;
    int incl = base + s;
    if (i < n) offs[i + 1] = incl;
    if (tid == 1023) bsum[blockIdx.x] = incl;
}
// fused scan2+scan3: every block redundantly scans bsum (<=64 entries) in wave 0, then adds
__global__ void scan23_k(int* __restrict__ offs, const int* __restrict__ bsum,
                         int nb, int n) {
    __shared__ int pre[64];
    int tid = threadIdx.x;
    if (tid < 64) {
        int v = (tid < nb) ? bsum[tid] : 0;
#pragma unroll
        for (int o = 1; o < 64; o <<= 1) { int t = __shfl_up(v, o); if (tid >= o) v += t; }
        pre[tid] = v;  // inclusive scan of block sums
    }
    __syncthreads();
    int i = blockIdx.x * 256 + tid;
    if (i == 0) offs[0] = 0;
    if (i < n) {
        int b = i >> 10;
        offs[i + 1] += (b > 0) ? pre[b - 1] : 0;
    }
}

// ---------------- fused: atomic-free CSR fill + layer-1 GEMM (one dispatch) ----------------
// blocks [0,fillBlocks): csr fill; rest: fp32-A hi/lo-split MFMA GEMM, row-major bf16 C, dinv-prescaled
__global__ __launch_bounds__(256) void fill_gemm1_k(const int* __restrict__ src,
                                                    const int* __restrict__ dst,
                                                    const u16* __restrict__ rank,
                                                    const int* __restrict__ offs,
                                                    u16* __restrict__ csr, int e, int fillBlocks,
                                                    const float* __restrict__ A,
                                                    const u16* __restrict__ Whi,
                                                    const u16* __restrict__ Wlo,
                                                    const float* __restrict__ dinv,
                                                    u16* __restrict__ C, int nrows) {
    if ((int)blockIdx.x < fillBlocks) {
        int i = blockIdx.x * 256 + threadIdx.x;
        if (i < e) csr[offs[dst[i]] + (int)rank[i]] = (u16)src[i];
        return;
    }
    constexpr int COLS = 128;
    int bid = blockIdx.x - fillBlocks;
    int wave = threadIdx.x >> 6, lane = threadIdx.x & 63;
    int r0 = bid * 64 + wave * 16;
    int arow = min(r0 + (lane & 15), nrows - 1);
    int kbase = (lane >> 4) * 8;

    bf16x8 ahi[4], alo[4];
#pragma unroll
    for (int ks = 0; ks < 4; ++ks) {
        const float* ap = &A[(long)arow * 128 + ks * 32 + kbase];
        float4 f0 = *(const float4*)ap;
        float4 f1 = *(const float4*)(ap + 4);
        float fv[8] = {f0.x, f0.y, f0.z, f0.w, f1.x, f1.y, f1.z, f1.w};
#pragma unroll
        for (int j = 0; j < 8; ++j) {
            u16 h = f2bf(fv[j]);
            ahi[ks][j] = (short)h;
            alo[ks][j] = (short)f2bf(fv[j] - bf2f(h));
        }
    }
    float dscale[4];
#pragma unroll
    for (int r = 0; r < 4; ++r) {
        int orow = r0 + (lane >> 4) * 4 + r;
        dscale[r] = (orow < nrows) ? dinv[orow] : 0.f;
    }
#pragma unroll
    for (int ct = 0; ct < COLS / 16; ct += 2) {
        f32x4 acc0 = {0.f, 0.f, 0.f, 0.f}, acc1 = {0.f, 0.f, 0.f, 0.f};
#pragma unroll
        for (int ks = 0; ks < 4; ++ks) {
            int fo0 = ((ct * 4 + ks) * 64 + lane) * 8;
            int fo1 = (((ct + 1) * 4 + ks) * 64 + lane) * 8;
            bf16x8 bhi0 = *(const bf16x8*)&Whi[fo0];
            bf16x8 blo0 = *(const bf16x8*)&Wlo[fo0];
            bf16x8 bhi1 = *(const bf16x8*)&Whi[fo1];
            bf16x8 blo1 = *(const bf16x8*)&Wlo[fo1];
            acc0 = __builtin_amdgcn_mfma_f32_16x16x32_bf16(ahi[ks], bhi0, acc0, 0, 0, 0);
            acc1 = __builtin_amdgcn_mfma_f32_16x16x32_bf16(ahi[ks], bhi1, acc1, 0, 0, 0);
            acc0 = __builtin_amdgcn_mfma_f32_16x16x32_bf16(alo[ks], bhi0, acc0, 0, 0, 0);
            acc1 = __builtin_amdgcn_mfma_f32_16x16x32_bf16(alo[ks], bhi1, acc1, 0, 0, 0);
            acc0 = __builtin_amdgcn_mfma_f32_16x16x32_bf16(ahi[ks], blo0, acc0, 0, 0, 0);
            acc1 = __builtin_amdgcn_mfma_f32_16x16x32_bf16(ahi[ks], blo1, acc1, 0, 0, 0);
        }
#pragma unroll
        for (int r = 0; r < 4; ++r) {
            int orow = r0 + (lane >> 4) * 4 + r;
            if (orow < nrows) {
                C[(long)orow * COLS + ct * 16 + (lane & 15)] = f2bf(acc0[r] * dscale[r]);
                C[(long)orow * COLS + (ct + 1) * 16 + (lane & 15)] = f2bf(acc1[r] * dscale[r]);
            }
        }
    }
}

// ---------------- layers 2/3 GEMM: bf16 A (2 MFMA), row-major bf16 C ----------------
template<int COLS>
__global__ __launch_bounds__(256) void mfma_gemm_bf16a_k(const u16* __restrict__ A,
                                                         const u16* __restrict__ Whi,
                                                         const u16* __restrict__ Wlo,
                                                         const float* __restrict__ dinv,
                                                         u16* __restrict__ C, int nrows) {
    int wave = threadIdx.x >> 6, lane = threadIdx.x & 63;
    int r0 = blockIdx.x * 64 + wave * 16;
    int arow = min(r0 + (lane & 15), nrows - 1);
    int kbase = (lane >> 4) * 8;

    bf16x8 a[4];
#pragma unroll
    for (int ks = 0; ks < 4; ++ks)
        a[ks] = *(const bf16x8*)&A[(long)arow * 128 + ks * 32 + kbase];

    float dscale[4];
#pragma unroll
    for (int r = 0; r < 4; ++r) {
        int orow = r0 + (lane >> 4) * 4 + r;
        dscale[r] = (orow < nrows) ? dinv[orow] : 0.f;
    }
#pragma unroll
    for (int ct = 0; ct < COLS / 16; ct += 2) {
        f32x4 acc0 = {0.f, 0.f, 0.f, 0.f}, acc1 = {0.f, 0.f, 0.f, 0.f};
#pragma unroll
        for (int ks = 0; ks < 4; ++ks) {
            int fo0 = ((ct * 4 + ks) * 64 + lane) * 8;
            int fo1 = (((ct + 1) * 4 + ks) * 64 + lane) * 8;
            bf16x8 bhi0 = *(const bf16x8*)&Whi[fo0];
            bf16x8 blo0 = *(const bf16x8*)&Wlo[fo0];
            bf16x8 bhi1 = *(const bf16x8*)&Whi[fo1];
            bf16x8 blo1 = *(const bf16x8*)&Wlo[fo1];
            acc0 = __builtin_amdgcn_mfma_f32_16x16x32_bf16(a[ks], bhi0, acc0, 0, 0, 0);
            acc1 = __builtin_amdgcn_mfma_f32_16x16x32_bf16(a[ks], bhi1, acc1, 0, 0, 0);
            acc0 = __builtin_amdgcn_mfma_f32_16x16x32_bf16(a[ks], blo0, acc0, 0, 0, 0);
            acc1 = __builtin_amdgcn_mfma_f32_16x16x32_bf16(a[ks], blo1, acc1, 0, 0, 0);
        }
#pragma unroll
        for (int r = 0; r < 4; ++r) {
            int orow = r0 + (lane >> 4) * 4 + r;
            if (orow < nrows) {
                C[(long)orow * COLS + ct * 16 + (lane & 15)] = f2bf(acc0[r] * dscale[r]);
                C[(long)orow * COLS + (ct + 1) * 16 + (lane & 15)] = f2bf(acc1[r] * dscale[r]);
            }
        }
    }
}

// ---------------- fused CSR-gather aggregate + bias + LayerNorm + ReLU (bf16 Cs/h) ----------------
__global__ __launch_bounds__(256) void agg_ln_relu_k(const u16* __restrict__ Cs,
                                                     const int* __restrict__ offs,
                                                     const u16* __restrict__ csr,
                                                     const float* __restrict__ dinv,
                                                     const float* __restrict__ bias,
                                                     const float* __restrict__ g,
                                                     const float* __restrict__ b,
                                                     u16* __restrict__ out, int n) {
    int wid = (blockIdx.x * 256 + threadIdx.x) >> 6;
    int lane = threadIdx.x & 63;
    if (wid >= n) return;
    const u32* C2 = (const u32*)Cs;
    u32 su = C2[(long)wid * 64 + lane];
    float ax = pk_lo(su), ay = pk_hi(su), bx2 = 0.f, by2 = 0.f;
    int beg = offs[wid], end = offs[wid + 1];
    int j = beg;
    while (j < end) {
        int take = min(64, end - j);
        int myidx = (lane < take) ? (int)csr[j + lane] : 0;
        int k = 0;
        for (; k + 8 <= take; k += 8) {
            int i0 = __shfl(myidx, k),     i1 = __shfl(myidx, k + 1);
            int i2 = __shfl(myidx, k + 2), i3 = __shfl(myidx, k + 3);
            int i4 = __shfl(myidx, k + 4), i5 = __shfl(myidx, k + 5);
            int i6 = __shfl(myidx, k + 6), i7 = __shfl(myidx, k + 7);
            u32 u0 = C2[(long)i0 * 64 + lane], u1 = C2[(long)i1 * 64 + lane];
            u32 u2 = C2[(long)i2 * 64 + lane], u3 = C2[(long)i3 * 64 + lane];
            u32 u4 = C2[(long)i4 * 64 + lane], u5 = C2[(long)i5 * 64 + lane];
            u32 u6 = C2[(long)i6 * 64 + lane], u7 = C2[(long)i7 * 64 + lane];
            ax += pk_lo(u0) + pk_lo(u1) + pk_lo(u2) + pk_lo(u3);
            ay += pk_hi(u0) + pk_hi(u1) + pk_hi(u2) + pk_hi(u3);
            bx2 += pk_lo(u4) + pk_lo(u5) + pk_lo(u6) + pk_lo(u7);
            by2 += pk_hi(u4) + pk_hi(u5) + pk_hi(u6) + pk_hi(u7);
        }
        for (; k < take; ++k) {
            int i0 = __shfl(myidx, k);
            u32 u0 = C2[(long)i0 * 64 + lane];
            ax += pk_lo(u0); ay += pk_hi(u0);
        }
        j += take;
    }
    float w = dinv[wid];
    float2 bia = ((const float2*)bias)[lane];
    float t0 = (ax + bx2) * w + bia.x;
    float t1 = (ay + by2) * w + bia.y;
    float s = t0 + t1;
#pragma unroll
    for (int off = 32; off; off >>= 1) s += __shfl_xor(s, off);
    float mu = s * (1.f / 128.f);
    float d0 = t0 - mu, d1 = t1 - mu;
    float v = d0 * d0 + d1 * d1;
#pragma unroll
    for (int off = 32; off; off >>= 1) v += __shfl_xor(v, off);
    float rstd = rsqrtf(v * (1.f / 128.f) + 1e-5f);
    float2 gv = ((const float2*)g)[lane];
    float2 bv = ((const float2*)b)[lane];
    float y0 = fmaxf(0.f, d0 * rstd * gv.x + bv.x);
    float y1 = fmaxf(0.f, d1 * rstd * gv.y + bv.y);
    ((u32*)out)[(long)wid * 64 + lane] = ((u32)f2bf(y1) << 16) | f2bf(y0);
}

// ---------------- fused CSR-gather aggregate + bias + log_softmax (bf16 Cs, 64-col) ----------------
__global__ __launch_bounds__(256) void agg_lsm_k(const u16* __restrict__ Cs,
                                                 const int* __restrict__ offs,
                                                 const u16* __restrict__ csr,
                                                 const float* __restrict__ dinv,
                                                 const float* __restrict__ b2,
                                                 float* __restrict__ out, int n) {
    int wid = (blockIdx.x * 256 + threadIdx.x) >> 6;
    int lane = threadIdx.x & 63;
    if (wid >= n) return;
    float aa = bf2f(Cs[(long)wid * 64 + lane]), ab = 0.f;
    int beg = offs[wid], end = offs[wid + 1];
    int j = beg;
    while (j < end) {
        int take = min(64, end - j);
        int myidx = (lane < take) ? (int)csr[j + lane] : 0;
        int k = 0;
        for (; k + 8 <= take; k += 8) {
            int i0 = __shfl(myidx, k),     i1 = __shfl(myidx, k + 1);
            int i2 = __shfl(myidx, k + 2), i3 = __shfl(myidx, k + 3);
            int i4 = __shfl(myidx, k + 4), i5 = __shfl(myidx, k + 5);
            int i6 = __shfl(myidx, k + 6), i7 = __shfl(myidx, k + 7);
            float v0 = bf2f(Cs[(long)i0 * 64 + lane]), v1 = bf2f(Cs[(long)i1 * 64 + lane]);
            float v2 = bf2f(Cs[(long)i2 * 64 + lane]), v3 = bf2f(Cs[(long)i3 * 64 + lane]);
            float v4 = bf2f(Cs[(long)i4 * 64 + lane]), v5 = bf2f(Cs[(long)i5 * 64 + lane]);
            float v6 = bf2f(Cs[(long)i6 * 64 + lane]), v7 = bf2f(Cs[(long)i7 * 64 + lane]);
            aa += v0 + v1 + v2 + v3;
            ab += v4 + v5 + v6 + v7;
        }
        for (; k < take; ++k) {
            int i0 = __shfl(myidx, k);
            aa += bf2f(Cs[(long)i0 * 64 + lane]);
        }
        j += take;
    }
    float v = (lane < 40) ? (aa + ab) * dinv[wid] + b2[lane] : -INFINITY;
    float m = v;
#pragma unroll
    for (int off = 32; off; off >>= 1) m = fmaxf(m, __shfl_xor(m, off));
    float e = (lane < 40) ? expf(v - m) : 0.f;
    float s = e;
#pragma unroll
    for (int off = 32; off; off >>= 1) s += __shfl_xor(s, off);
    float r = v - m - logf(s);
    if (lane < 40) out[(long)wid * 40 + lane] = r;
}

extern "C" void kernel_launch(void* const* d_in, const int* in_sizes, int n_in,
                              void* d_out, int out_size, void* d_ws, size_t ws_size,
                              hipStream_t stream) {
    const float* x    = (const float*)d_in[0];
    const float* W0   = (const float*)d_in[1];
    const float* b0   = (const float*)d_in[2];
    const float* W1   = (const float*)d_in[3];
    const float* b1   = (const float*)d_in[4];
    const float* W2   = (const float*)d_in[5];
    const float* b2   = (const float*)d_in[6];
    const float* ln1g = (const float*)d_in[7];
    const float* ln1b = (const float*)d_in[8];
    const float* ln2g = (const float*)d_in[9];
    const float* ln2b = (const float*)d_in[10];
    const int*   ei   = (const int*)d_in[11];

    const int N = in_sizes[0] / 128;   // 50000
    const int E = in_sizes[11] / 2;    // 800000
    const int* esrc = ei;
    const int* edst = ei + E;
    float* out = (float*)d_out;

    const int Npad = ((N + 255) / 256) * 256;

    int* counts  = (int*)d_ws;                        // Npad
    int* offs    = counts + Npad;                     // Npad (N+1 used)
    int* bsum    = offs + Npad;                       // 64
    u16* rank16  = (u16*)(bsum + 64);                 // E
    u16* csr16   = rank16 + E;                        // E
    float* dinv  = (float*)(csr16 + E);               // Npad
    u16* bufA    = (u16*)(dinv + Npad);               // N*128 bf16 (Cs)
    u16* bufB    = bufA + (size_t)N * 128;            // N*128 bf16 (h)
    u16* w0hi    = bufB + (size_t)N * 128;
    u16* w0lo    = w0hi + 16384;
    u16* w1hi    = w0lo + 16384;
    u16* w1lo    = w1hi + 16384;
    u16* w2hi    = w1lo + 16384;
    u16* w2lo    = w2hi + 8192;

    dim3 blk(256);
    int gN = (N + 255) / 256, gE = (E + 255) / 256;
    int nb1024 = (N + 1023) / 1024;
    int gG = (N + 63) / 64;
    int gW = (N + 3) / 4;

    // 1. zero + weight prepack
    init_k<<<gN + 160, blk, 0, stream>>>(counts, N, gN, W0, W1, W2,
                                         w0hi, w0lo, w1hi, w1lo, w2hi, w2lo);
    // 2. count + rank
    count_rank_k<<<gE, blk, 0, stream>>>(edst, counts, rank16, E);
    // 3. block-local scan + dinv
    scan1_k<<<nb1024, 1024, 0, stream>>>(counts, offs, bsum, dinv, N);
    // 4. cross-block scan fixup
    scan23_k<<<gN, blk, 0, stream>>>(offs, bsum, nb1024, N);
    // 5. CSR fill + layer-1 GEMM (fused dispatch)
    fill_gemm1_k<<<gE + gG, blk, 0, stream>>>(esrc, edst, rank16, offs, csr16, E, gE,
                                              x, w0hi, w0lo, dinv, bufA, N);
    // 6. agg + LN1 + ReLU
    agg_ln_relu_k<<<gW, blk, 0, stream>>>(bufA, offs, csr16, dinv, b0, ln1g, ln1b, bufB, N);
    // 7. layer-2 GEMM
    mfma_gemm_bf16a_k<128><<<gG, blk, 0, stream>>>(bufB, w1hi, w1lo, dinv, bufA, N);
    // 8. agg + LN2 + ReLU
    agg_ln_relu_k<<<gW, blk, 0, stream>>>(bufA, offs, csr16, dinv, b1, ln2g, ln2b, bufB, N);
    // 9. layer-3 GEMM
    mfma_gemm_bf16a_k<64><<<gG, blk, 0, stream>>>(bufB, w2hi, w2lo, dinv, bufA, N);
    // 10. agg + bias + log_softmax
    agg_lsm_k<<<gW, blk, 0, stream>>>(bufA, offs, csr16, dinv, b2, out, N);
}